// Round 12
// baseline (176.992 us; speedup 1.0000x reference)
//
#include <hip/hip_runtime.h>

// graph_56006373539875: per-edge spring-force scatter.
// R1: global f32 atomics -> 1881us. R2: LDS f32 redundant scan -> 240us.
// R3: de-gathered scan -> 238us. R4: bucket+f32 consume -> 340us.
// R5-R7: i64-packed consume + ballot/ring emit -> 144us (emit 110us).
// R8-R9: fused u64 scan -> 136us; latency wall at 16 waves/CU.
// R10: lean emit (LDS-counter slots + direct 8B stores) -> 135.7us, emit 98.
// R11: occupancy 32->50% => emit EXACTLY 98us again. Per-CU TA/VMEM
//      address pipe saturated (~30M scattered lane-addresses @ ~2cyc);
//      emit is at its structural floor for this decomposition.
// R12: recover the non-emit ~37us: fuse count+scan INTO emit. Static
//      range segments (cap = E*2/5 + 22-sigma slack); each wave counts
//      its L1-resident chunk in registers (pass1, idle VALU pipe), one
//      global atomicAdd per (wave,range) reserves exact slots, then
//      pass2 = R10 emit. 5 kernels -> 4; no waveprefix traffic.

#define NR5    5
#define NWAVE  4096
#define EWAVES 8                 // emit waves/block
#define K3T    (EWAVES * 64)     // 512
#define NBLD3  (NWAVE / EWAVES)  // 512 blocks
#define K4T    1024
#define NSLICE 44
#define QSCALE 4096.0f

struct __attribute__((packed, aligned(4))) F3 { float x, y, z; };

// ---------------- K0: zero the 5 global range counters --------------------
__global__ void init_kernel(unsigned* __restrict__ gcnt) {
    if (threadIdx.x < NR5) gcnt[threadIdx.x] = 0u;
}

// ---------------- K3: fused count + reserve + emit -------------------------
__global__ __launch_bounds__(K3T) void emit_kernel(
    const float* __restrict__ points, const float* __restrict__ force,
    const int* __restrict__ ea, const int* __restrict__ eb,
    unsigned* __restrict__ gcnt,             // [NR5] running totals
    uint2* __restrict__ entries,             // [NR5*cap] {id|qx<<16, qy|qz<<16}
    int n_edges, int chunk, int range, unsigned magic, unsigned cap)
{
    __shared__ unsigned cnt[EWAVES][NR5];
    const int wslot = (int)threadIdx.x >> 6;
    const int lane  = (int)threadIdx.x & 63;
    const int wid   = blockIdx.x * EWAVES + wslot;

    const int e0 = min(n_edges, wid * chunk);
    const int e1 = min(n_edges, e0 + chunk);
    const int nvec = (e1 - e0) & ~3;

    const int4*   ea4 = (const int4*)(ea + e0);
    const int4*   eb4 = (const int4*)(eb + e0);
    const float4* ff4 = (const float4*)(force + e0);

    // ---- pass 1: register count of this wave's chunk (L1-resident) ----
    unsigned c[NR5];
#pragma unroll
    for (int j = 0; j < NR5; ++j) c[j] = 0;
    for (int g = lane; g < (nvec >> 2); g += 64) {
        int4 a4 = ea4[g];
        int4 b4 = eb4[g];
        unsigned r0 = __umulhi((unsigned)a4.x, magic), s0 = __umulhi((unsigned)b4.x, magic);
        unsigned r1 = __umulhi((unsigned)a4.y, magic), s1 = __umulhi((unsigned)b4.y, magic);
        unsigned r2 = __umulhi((unsigned)a4.z, magic), s2 = __umulhi((unsigned)b4.z, magic);
        unsigned r3 = __umulhi((unsigned)a4.w, magic), s3 = __umulhi((unsigned)b4.w, magic);
#pragma unroll
        for (int j = 0; j < NR5; ++j)
            c[j] += (r0 == (unsigned)j) + (s0 == (unsigned)j)
                  + (r1 == (unsigned)j) + (s1 == (unsigned)j)
                  + (r2 == (unsigned)j) + (s2 == (unsigned)j)
                  + (r3 == (unsigned)j) + (s3 == (unsigned)j);
    }
    for (int e = e0 + nvec + lane; e < e1; e += 64) {
        unsigned ra = __umulhi((unsigned)ea[e], magic);
        unsigned rb = __umulhi((unsigned)eb[e], magic);
#pragma unroll
        for (int j = 0; j < NR5; ++j)
            c[j] += (ra == (unsigned)j) + (rb == (unsigned)j);
    }
    // wave-reduce each range count, broadcast to all lanes
    unsigned tot[NR5];
#pragma unroll
    for (int j = 0; j < NR5; ++j) {
        unsigned v = c[j];
#pragma unroll
        for (int off = 32; off > 0; off >>= 1) v += __shfl_down(v, off);
        tot[j] = __shfl(v, 0);
    }
    // lane j (j<NR5) reserves tot[j] slots in range j
    if (lane < NR5) {
        unsigned my = (lane == 0) ? tot[0] : (lane == 1) ? tot[1]
                    : (lane == 2) ? tot[2] : (lane == 3) ? tot[3] : tot[4];
        unsigned base = atomicAdd(&gcnt[lane], my);
        cnt[wslot][lane] = (unsigned)lane * cap + base;
    }
    __syncthreads();   // uniform: every wave executes exactly once

    // ---- pass 2: compute + slot-alloc + store (R10 structure) ----
    const F3* __restrict__ P = (const F3*)points;

#define PROCE(pa, pb, fsc, aa, bb)                                               \
    {                                                                            \
        float vx = pb.x - pa.x, vy = pb.y - pa.y, vz = pb.z - pa.z;              \
        float s  = -(fsc) * rsqrtf(vx * vx + vy * vy + vz * vz);                 \
        int qx = __float2int_rn(s * vx * QSCALE);                                \
        int qy = __float2int_rn(s * vy * QSCALE);                                \
        int qz = __float2int_rn(s * vz * QSCALE);                                \
        qx = max(-32767, min(32767, qx));                                        \
        qy = max(-32767, min(32767, qy));                                        \
        qz = max(-32767, min(32767, qz));                                        \
        unsigned ra = __umulhi((unsigned)(aa), magic);                           \
        unsigned rb = __umulhi((unsigned)(bb), magic);                           \
        unsigned ida = (unsigned)(aa) - ra * (unsigned)range;                    \
        unsigned idb = (unsigned)(bb) - rb * (unsigned)range;                    \
        uint2 entA, entB;                                                        \
        entA.x = ida | ((unsigned)(unsigned short)(short)qx << 16);              \
        entA.y = (unsigned)(unsigned short)(short)qy                             \
               | ((unsigned)(unsigned short)(short)qz << 16);                    \
        entB.x = idb | ((unsigned)(unsigned short)(short)(-qx) << 16);           \
        entB.y = (unsigned)(unsigned short)(short)(-qy)                          \
               | ((unsigned)(unsigned short)(short)(-qz) << 16);                 \
        unsigned sA = atomicAdd(&cnt[wslot][ra], 1u);                            \
        sA = min(sA, (ra + 1u) * cap - 1u);                                      \
        entries[sA] = entA;                                                      \
        unsigned sB = atomicAdd(&cnt[wslot][rb], 1u);                            \
        sB = min(sB, (rb + 1u) * cap - 1u);                                      \
        entries[sB] = entB;                                                      \
    }

    for (int g = lane; g < (nvec >> 2); g += 64) {
        int4   a4 = ea4[g];
        int4   b4 = eb4[g];
        float4 f4 = ff4[g];
        // issue all 8 gathers before any math (MLP)
        F3 pa0 = P[a4.x]; F3 pb0 = P[b4.x];
        F3 pa1 = P[a4.y]; F3 pb1 = P[b4.y];
        F3 pa2 = P[a4.z]; F3 pb2 = P[b4.z];
        F3 pa3 = P[a4.w]; F3 pb3 = P[b4.w];
        PROCE(pa0, pb0, f4.x, a4.x, b4.x)
        PROCE(pa1, pb1, f4.y, a4.y, b4.y)
        PROCE(pa2, pb2, f4.z, a4.z, b4.z)
        PROCE(pa3, pb3, f4.w, a4.w, b4.w)
    }
    for (int e = e0 + nvec + lane; e < e1; e += 64) {
        int a = ea[e], b = eb[e];
        F3 pa = P[a], pb = P[b];
        float f = force[e];
        PROCE(pa, pb, f, a, b)
    }
#undef PROCE
}

// ---------------- K4: dense consume, ONE ds_add_u64 per entry -------------
__global__ __launch_bounds__(K4T) void consume_kernel(
    const ushort4* __restrict__ entries, const unsigned* __restrict__ gcnt,
    unsigned long long* __restrict__ partial64,   // [NSLICE][np_pad]
    int np_pad, int range, unsigned cap)
{
    extern __shared__ unsigned long long lds64[];   // [range]
    const int r     = blockIdx.x % NR5;
    const int slice = blockIdx.x / NR5;

    const unsigned base = (unsigned)r * cap;
    const unsigned cnt  = min(gcnt[r], cap);
    const unsigned lo = base + (unsigned)((unsigned long long)cnt * slice / NSLICE);
    const unsigned hi = base + (unsigned)((unsigned long long)cnt * (slice + 1) / NSLICE);

    for (int w = threadIdx.x; w < range; w += K4T) lds64[w] = 0ULL;
    __syncthreads();

    for (unsigned i = lo + threadIdx.x; i < hi; i += K4T) {
        ushort4 q = entries[i];
        long long v = (long long)(short)q.y
                    + ((long long)(short)q.z << 21)
                    + ((long long)(short)q.w << 42);
        atomicAdd(&lds64[q.x], (unsigned long long)v);
    }
    __syncthreads();

    unsigned long long* dst = partial64 + (size_t)slice * (size_t)np_pad
                            + (size_t)r * (size_t)range;
    for (int w = threadIdx.x; w < range; w += K4T) dst[w] = lds64[w];
}

// ---------------- K5: exact u64 reduce -> decode -> + ext -----------------
__global__ void reduce64_kernel(const float* __restrict__ ext,
                                const unsigned long long* __restrict__ partial64,
                                float* __restrict__ out, int n_points, int np_pad)
{
    int i = blockIdx.x * blockDim.x + threadIdx.x;
    if (i >= n_points) return;
    unsigned long long t = 0ULL;
#pragma unroll 4
    for (int c = 0; c < NSLICE; ++c)
        t += partial64[(size_t)c * (size_t)np_pad + i];

    long long T = (long long)t;
    long long X = ((long long)((unsigned long long)T << 43)) >> 43;
    T = (T - X) >> 21;
    long long Y = ((long long)((unsigned long long)T << 43)) >> 43;
    T = (T - Y) >> 21;
    long long Z = ((long long)((unsigned long long)T << 42)) >> 42;

    const float inv = 1.0f / QSCALE;
    out[3 * i + 0] = ext[3 * i + 0] + (float)X * inv;
    out[3 * i + 1] = ext[3 * i + 1] + (float)Y * inv;
    out[3 * i + 2] = ext[3 * i + 2] + (float)Z * inv;
}

// ---------------- fallback: fused u64 scan (R8, known-pass) ----------------
#define NB5FB 48
#define SCANT 1024
__global__ __launch_bounds__(SCANT) void scan64_kernel(
    const float* __restrict__ points, const float* __restrict__ force,
    const int* __restrict__ ea, const int* __restrict__ eb,
    unsigned long long* __restrict__ partial64,   // [NB5FB][np_pad]
    int n_edges, int np_pad, int range)
{
    extern __shared__ unsigned long long lds64[];
    const int r = blockIdx.x / NB5FB;
    const int c = blockIdx.x % NB5FB;
    const int node0 = r * range;
    for (int w = threadIdx.x; w < range; w += SCANT) lds64[w] = 0ULL;
    __syncthreads();
    const F3* __restrict__ P = (const F3*)points;
    const int chunk = (n_edges + NB5FB - 1) / NB5FB;
    const int e0 = c * chunk, e1 = min(n_edges, e0 + chunk);
    for (int e = e0 + (int)threadIdx.x; e < e1; e += SCANT) {
        int a = ea[e], b = eb[e];
        int la = a - node0, lb = b - node0;
        bool ha = (unsigned)la < (unsigned)range;
        bool hb = (unsigned)lb < (unsigned)range;
        if (ha || hb) {
            F3 pa = P[a], pb = P[b];
            float vx = pb.x - pa.x, vy = pb.y - pa.y, vz = pb.z - pa.z;
            float s = -force[e] * rsqrtf(vx * vx + vy * vy + vz * vz);
            int qx = __float2int_rn(s * vx * QSCALE);
            int qy = __float2int_rn(s * vy * QSCALE);
            int qz = __float2int_rn(s * vz * QSCALE);
            qx = max(-32767, min(32767, qx));
            qy = max(-32767, min(32767, qy));
            qz = max(-32767, min(32767, qz));
            long long v = (long long)qx + ((long long)qy << 21) + ((long long)qz << 42);
            if (ha) atomicAdd(&lds64[la], (unsigned long long)v);
            if (hb) atomicAdd(&lds64[lb], (unsigned long long)(-v));
        }
    }
    __syncthreads();
    unsigned long long* dst = partial64 + (size_t)c * (size_t)np_pad + node0;
    for (int w = threadIdx.x; w < range; w += SCANT) dst[w] = lds64[w];
}

__global__ void reduce64fb_kernel(const float* __restrict__ ext,
                                  const unsigned long long* __restrict__ partial64,
                                  float* __restrict__ out, int n_points, int np_pad)
{
    int i = blockIdx.x * blockDim.x + threadIdx.x;
    if (i >= n_points) return;
    unsigned long long t = 0ULL;
#pragma unroll 4
    for (int c = 0; c < NB5FB; ++c)
        t += partial64[(size_t)c * (size_t)np_pad + i];
    long long T = (long long)t;
    long long X = ((long long)((unsigned long long)T << 43)) >> 43;
    T = (T - X) >> 21;
    long long Y = ((long long)((unsigned long long)T << 43)) >> 43;
    T = (T - Y) >> 21;
    long long Z = ((long long)((unsigned long long)T << 42)) >> 42;
    const float inv = 1.0f / QSCALE;
    out[3 * i + 0] = ext[3 * i + 0] + (float)X * inv;
    out[3 * i + 1] = ext[3 * i + 1] + (float)Y * inv;
    out[3 * i + 2] = ext[3 * i + 2] + (float)Z * inv;
}

extern "C" void kernel_launch(void* const* d_in, const int* in_sizes, int n_in,
                              void* d_out, int out_size, void* d_ws, size_t ws_size,
                              hipStream_t stream) {
    const float* points = (const float*)d_in[0];
    const float* ext_f  = (const float*)d_in[1];
    const float* force  = (const float*)d_in[2];
    const int*   ea     = (const int*)d_in[3];
    const int*   eb     = (const int*)d_in[4];
    float* out = (float*)d_out;
    char*  ws  = (char*)d_ws;

    const int n_edges  = in_sizes[2];
    const int total    = out_size;                       // n_points*3
    const int n_points = total / 3;

    const int range5  = (n_points + NR5 - 1) / NR5;      // 20000
    const int np_pad  = range5 * NR5;
    const unsigned magic = (unsigned)((0x100000000ULL + range5 - 1) / (unsigned)range5);
    const int chunk = (((n_edges + NWAVE - 1) / NWAVE) + 3) & ~3;   // x4 aligned

    // static segment capacity: mean + 1.25% slack (~22 sigma), 64-aligned
    const unsigned epr = (unsigned)(((unsigned long long)2 * n_edges) / NR5);
    const unsigned cap = (epr + epr / 80 + 63u) & ~63u;             // ~2.592M

    const size_t lds_consume = (size_t)range5 * sizeof(unsigned long long); // 160000
    const size_t entries_b = (size_t)NR5 * cap * sizeof(uint2);             // ~103.7MB
    const size_t partial_b = (size_t)NSLICE * (size_t)np_pad * sizeof(unsigned long long); // 35.2MB
    const size_t need_new  = entries_b + partial_b + 64;

    const size_t partfb_b  = (size_t)NB5FB * (size_t)np_pad * sizeof(unsigned long long);

    hipFuncSetAttribute((const void*)consume_kernel,
                        hipFuncAttributeMaxDynamicSharedMemorySize, (int)lds_consume);
    hipFuncSetAttribute((const void*)scan64_kernel,
                        hipFuncAttributeMaxDynamicSharedMemorySize, (int)lds_consume);

    const int rb = 256;

    if (range5 <= 0xFFFF && lds_consume <= 160 * 1024 && ws_size >= need_new) {
        uint2* entries = (uint2*)ws;
        unsigned long long* partial64 = (unsigned long long*)(ws + entries_b);
        unsigned* gcnt = (unsigned*)(ws + ws_size - 64);

        init_kernel<<<1, 64, 0, stream>>>(gcnt);
        emit_kernel<<<NBLD3, K3T, 0, stream>>>(
            points, force, ea, eb, gcnt, entries,
            n_edges, chunk, range5, magic, cap);
        consume_kernel<<<NR5 * NSLICE, K4T, lds_consume, stream>>>(
            (const ushort4*)entries, gcnt, partial64, np_pad, range5, cap);
        reduce64_kernel<<<(n_points + rb - 1) / rb, rb, 0, stream>>>(
            ext_f, partial64, out, n_points, np_pad);
    } else if (lds_consume <= 160 * 1024 && ws_size >= partfb_b) {
        unsigned long long* partial64 = (unsigned long long*)ws;
        scan64_kernel<<<NR5 * NB5FB, SCANT, lds_consume, stream>>>(
            points, force, ea, eb, partial64, n_edges, np_pad, range5);
        reduce64fb_kernel<<<(n_points + rb - 1) / rb, rb, 0, stream>>>(
            ext_f, partial64, out, n_points, np_pad);
    } else {
        // minimal fallback: direct global atomics (R1 structure)
        hipMemcpyAsync(d_out, (const void*)ext_f, (size_t)total * sizeof(float),
                       hipMemcpyDeviceToDevice, stream);
        // reuse scan64 path impossible; emit simple per-edge atomic kernel
        // (correct but slow; only hit if ws is tiny)
        struct L {
            static __global__ void k(const float* P, const float* F,
                                     const int* A, const int* B, float* O, int n) {
                int e = blockIdx.x * blockDim.x + threadIdx.x;
                if (e >= n) return;
                int a = A[e], b = B[e];
                float ax = P[3*a], ay = P[3*a+1], az = P[3*a+2];
                float bx = P[3*b], by = P[3*b+1], bz = P[3*b+2];
                float vx = bx-ax, vy = by-ay, vz = bz-az;
                float s = -F[e] * rsqrtf(vx*vx+vy*vy+vz*vz);
                atomicAdd(&O[3*a+0], s*vx); atomicAdd(&O[3*a+1], s*vy); atomicAdd(&O[3*a+2], s*vz);
                atomicAdd(&O[3*b+0], -s*vx); atomicAdd(&O[3*b+1], -s*vy); atomicAdd(&O[3*b+2], -s*vz);
            }
        };
        L::k<<<(n_edges + 255) / 256, 256, 0, stream>>>(points, force, ea, eb, out, n_edges);
    }
}

// Round 13
// 152.479 us; speedup vs baseline: 1.1608x; 1.1608x over previous
//
#include <hip/hip_runtime.h>

// graph_56006373539875: per-edge spring-force scatter.
// R1 1881us -> R2 240 -> R5 165 -> R7 144 -> R10 135.7 (best).
// R10: emit 98us = wall. R11: occupancy 32->50% => emit unchanged =>
//      per-CU SHARED pipe saturated. R12: count fusion regressed (154us).
// R13: test the remaining suspect for emit's wall: SAME-ADDRESS LDS
//      atomic-with-return serialization (5 counters/wave, ~13 colliding
//      lanes must get distinct return values -> LDS pipe serializes;
//      per-CU shared => occupancy-invariant, matches R11 exactly).
//      Fix: fan counters out 8x -> per-(wave,range,8-lane-group), 40
//      counters/wave, avg 1.6 collisions. Static range segments (r*cap),
//      group-granular count + 2-phase scan. Zero global atomics.

#define NR5    5
#define NGRP   8
#define NROW   (NR5 * NGRP)      // 40
#define NWAVE  4096
#define K1T    1024              // count: 16 waves/block -> 256 blocks
#define EWAVES 8
#define K3T    (EWAVES * 64)     // 512
#define NBLD3  (NWAVE / EWAVES)  // 512
#define K4T    1024
#define NSLICE 44
#define QSCALE 4096.0f

struct __attribute__((packed, aligned(4))) F3 { float x, y, z; };

// ---------------- K1: per-(wave,range,lane-group) counts ------------------
__global__ __launch_bounds__(K1T) void count_kernel(
    const int* __restrict__ ea, const int* __restrict__ eb,
    unsigned* __restrict__ counts,           // [NROW][NWAVE]
    int n_edges, int chunk, unsigned magic)
{
    const int wid  = blockIdx.x * (K1T / 64) + ((int)threadIdx.x >> 6);
    const int lane = (int)threadIdx.x & 63;
    const int e0 = min(n_edges, wid * chunk);
    const int e1 = min(n_edges, e0 + chunk);
    const int nvec = (e1 - e0) & ~3;

    unsigned c[NR5];
#pragma unroll
    for (int j = 0; j < NR5; ++j) c[j] = 0;

    const int4* ea4 = (const int4*)(ea + e0);
    const int4* eb4 = (const int4*)(eb + e0);
    for (int g = lane; g < (nvec >> 2); g += 64) {
        int4 a4 = ea4[g];
        int4 b4 = eb4[g];
        unsigned r0 = __umulhi((unsigned)a4.x, magic), s0 = __umulhi((unsigned)b4.x, magic);
        unsigned r1 = __umulhi((unsigned)a4.y, magic), s1 = __umulhi((unsigned)b4.y, magic);
        unsigned r2 = __umulhi((unsigned)a4.z, magic), s2 = __umulhi((unsigned)b4.z, magic);
        unsigned r3 = __umulhi((unsigned)a4.w, magic), s3 = __umulhi((unsigned)b4.w, magic);
#pragma unroll
        for (int j = 0; j < NR5; ++j)
            c[j] += (r0 == (unsigned)j) + (s0 == (unsigned)j)
                  + (r1 == (unsigned)j) + (s1 == (unsigned)j)
                  + (r2 == (unsigned)j) + (s2 == (unsigned)j)
                  + (r3 == (unsigned)j) + (s3 == (unsigned)j);
    }
    for (int e = e0 + nvec + lane; e < e1; e += 64) {
        unsigned ra = __umulhi((unsigned)ea[e], magic);
        unsigned rb = __umulhi((unsigned)eb[e], magic);
#pragma unroll
        for (int j = 0; j < NR5; ++j)
            c[j] += (ra == (unsigned)j) + (rb == (unsigned)j);
    }
    // reduce within each 8-lane group; lane 8k holds group k's sum
#pragma unroll
    for (int j = 0; j < NR5; ++j) {
        unsigned v = c[j];
        v += __shfl_down(v, 1);
        v += __shfl_down(v, 2);
        v += __shfl_down(v, 4);
        if ((lane & 7) == 0)
            counts[(j * NGRP + (lane >> 3)) * NWAVE + wid] = v;
    }
}

// ---------------- K2: per-row prefix + in-range row offsets ---------------
// grid = NR5 blocks x 512 threads (8 waves). Wave g scans row r*8+g.
__global__ __launch_bounds__(512) void scan_kernel(
    const unsigned* __restrict__ counts,     // [NROW][NWAVE]
    unsigned* __restrict__ waveprefix,       // [NROW][NWAVE] row-local excl
    unsigned* __restrict__ rowoffset,        // [NROW] in-range offset of row
    unsigned* __restrict__ rangetotals)      // [NR5]
{
    __shared__ unsigned rowtot[NGRP];
    const int r    = blockIdx.x;
    const int g    = (int)threadIdx.x >> 6;
    const int lane = (int)threadIdx.x & 63;
    const int row  = r * NGRP + g;

    unsigned running = 0;
    for (int c = 0; c < NWAVE / 64; ++c) {
        const int idx = c * 64 + lane;
        unsigned v = counts[row * NWAVE + idx];
        const unsigned orig = v;
#pragma unroll
        for (int off = 1; off < 64; off <<= 1) {
            unsigned t = __shfl_up(v, off);
            if (lane >= off) v += t;
        }
        waveprefix[row * NWAVE + idx] = running + v - orig;
        running += __shfl(v, 63);
    }
    if (lane == 0) rowtot[g] = running;
    __syncthreads();
    if (threadIdx.x == 0) {
        unsigned run = 0;
        for (int k = 0; k < NGRP; ++k) {
            rowoffset[r * NGRP + k] = run;
            run += rowtot[k];
        }
        rangetotals[r] = run;
    }
}

// ---------------- K3: emit with 8x fanned-out LDS slot counters -----------
__global__ __launch_bounds__(K3T) void emit_kernel(
    const float* __restrict__ points, const float* __restrict__ force,
    const int* __restrict__ ea, const int* __restrict__ eb,
    const unsigned* __restrict__ waveprefix, const unsigned* __restrict__ rowoffset,
    uint2* __restrict__ entries,             // [NR5*cap]
    int n_edges, int chunk, int range, unsigned magic, unsigned cap)
{
    __shared__ unsigned cnt[EWAVES][NROW];
    const int wslot = (int)threadIdx.x >> 6;
    const int lane  = (int)threadIdx.x & 63;
    const int wid   = blockIdx.x * EWAVES + wslot;

    if (lane < NROW) {
        cnt[wslot][lane] = (unsigned)(lane >> 3) * cap   // static range segment
                         + rowoffset[lane]
                         + waveprefix[lane * NWAVE + wid];
    }
    __syncthreads();

    const F3* __restrict__ P = (const F3*)points;
    const int e0 = min(n_edges, wid * chunk);
    const int e1 = min(n_edges, e0 + chunk);
    const int nvec = (e1 - e0) & ~3;

    const int4*   ea4 = (const int4*)(ea + e0);
    const int4*   eb4 = (const int4*)(eb + e0);
    const float4* ff4 = (const float4*)(force + e0);
    const int grp = lane >> 3;

#define PROCE(pa, pb, fsc, aa, bb)                                               \
    {                                                                            \
        float vx = pb.x - pa.x, vy = pb.y - pa.y, vz = pb.z - pa.z;              \
        float s  = -(fsc) * rsqrtf(vx * vx + vy * vy + vz * vz);                 \
        int qx = __float2int_rn(s * vx * QSCALE);                                \
        int qy = __float2int_rn(s * vy * QSCALE);                                \
        int qz = __float2int_rn(s * vz * QSCALE);                                \
        qx = max(-32767, min(32767, qx));                                        \
        qy = max(-32767, min(32767, qy));                                        \
        qz = max(-32767, min(32767, qz));                                        \
        unsigned ra = __umulhi((unsigned)(aa), magic);                           \
        unsigned rb = __umulhi((unsigned)(bb), magic);                           \
        unsigned ida = (unsigned)(aa) - ra * (unsigned)range;                    \
        unsigned idb = (unsigned)(bb) - rb * (unsigned)range;                    \
        uint2 entA, entB;                                                        \
        entA.x = ida | ((unsigned)(unsigned short)(short)qx << 16);              \
        entA.y = (unsigned)(unsigned short)(short)qy                             \
               | ((unsigned)(unsigned short)(short)qz << 16);                    \
        entB.x = idb | ((unsigned)(unsigned short)(short)(-qx) << 16);           \
        entB.y = (unsigned)(unsigned short)(short)(-qy)                          \
               | ((unsigned)(unsigned short)(short)(-qz) << 16);                 \
        unsigned sA = atomicAdd(&cnt[wslot][ra * NGRP + grp], 1u);               \
        sA = min(sA, (ra + 1u) * cap - 1u);                                      \
        entries[sA] = entA;                                                      \
        unsigned sB = atomicAdd(&cnt[wslot][rb * NGRP + grp], 1u);               \
        sB = min(sB, (rb + 1u) * cap - 1u);                                      \
        entries[sB] = entB;                                                      \
    }

    for (int g = lane; g < (nvec >> 2); g += 64) {
        int4   a4 = ea4[g];
        int4   b4 = eb4[g];
        float4 f4 = ff4[g];
        F3 pa0 = P[a4.x]; F3 pb0 = P[b4.x];
        F3 pa1 = P[a4.y]; F3 pb1 = P[b4.y];
        F3 pa2 = P[a4.z]; F3 pb2 = P[b4.z];
        F3 pa3 = P[a4.w]; F3 pb3 = P[b4.w];
        PROCE(pa0, pb0, f4.x, a4.x, b4.x)
        PROCE(pa1, pb1, f4.y, a4.y, b4.y)
        PROCE(pa2, pb2, f4.z, a4.z, b4.z)
        PROCE(pa3, pb3, f4.w, a4.w, b4.w)
    }
    for (int e = e0 + nvec + lane; e < e1; e += 64) {
        int a = ea[e], b = eb[e];
        F3 pa = P[a], pb = P[b];
        float f = force[e];
        PROCE(pa, pb, f, a, b)
    }
#undef PROCE
}

// ---------------- K4: dense consume, ONE ds_add_u64 per entry -------------
__global__ __launch_bounds__(K4T) void consume_kernel(
    const ushort4* __restrict__ entries, const unsigned* __restrict__ rangetotals,
    unsigned long long* __restrict__ partial64,   // [NSLICE][np_pad]
    int np_pad, int range, unsigned cap)
{
    extern __shared__ unsigned long long lds64[];   // [range]
    const int r     = blockIdx.x % NR5;
    const int slice = blockIdx.x / NR5;

    const unsigned base = (unsigned)r * cap;
    const unsigned cnt  = min(rangetotals[r], cap);
    const unsigned lo = base + (unsigned)((unsigned long long)cnt * slice / NSLICE);
    const unsigned hi = base + (unsigned)((unsigned long long)cnt * (slice + 1) / NSLICE);

    for (int w = threadIdx.x; w < range; w += K4T) lds64[w] = 0ULL;
    __syncthreads();

    for (unsigned i = lo + threadIdx.x; i < hi; i += K4T) {
        ushort4 q = entries[i];
        long long v = (long long)(short)q.y
                    + ((long long)(short)q.z << 21)
                    + ((long long)(short)q.w << 42);
        atomicAdd(&lds64[q.x], (unsigned long long)v);
    }
    __syncthreads();

    unsigned long long* dst = partial64 + (size_t)slice * (size_t)np_pad
                            + (size_t)r * (size_t)range;
    for (int w = threadIdx.x; w < range; w += K4T) dst[w] = lds64[w];
}

// ---------------- K5: exact u64 reduce -> decode -> + ext -----------------
__global__ void reduce64_kernel(const float* __restrict__ ext,
                                const unsigned long long* __restrict__ partial64,
                                float* __restrict__ out, int n_points, int np_pad)
{
    int i = blockIdx.x * blockDim.x + threadIdx.x;
    if (i >= n_points) return;
    unsigned long long t = 0ULL;
#pragma unroll 4
    for (int c = 0; c < NSLICE; ++c)
        t += partial64[(size_t)c * (size_t)np_pad + i];

    long long T = (long long)t;
    long long X = ((long long)((unsigned long long)T << 43)) >> 43;
    T = (T - X) >> 21;
    long long Y = ((long long)((unsigned long long)T << 43)) >> 43;
    T = (T - Y) >> 21;
    long long Z = ((long long)((unsigned long long)T << 42)) >> 42;

    const float inv = 1.0f / QSCALE;
    out[3 * i + 0] = ext[3 * i + 0] + (float)X * inv;
    out[3 * i + 1] = ext[3 * i + 1] + (float)Y * inv;
    out[3 * i + 2] = ext[3 * i + 2] + (float)Z * inv;
}

// ---------------- fallback: fused u64 scan (R8, known 138us) --------------
#define NB5FB 48
#define SCANT 1024
__global__ __launch_bounds__(SCANT) void scan64_kernel(
    const float* __restrict__ points, const float* __restrict__ force,
    const int* __restrict__ ea, const int* __restrict__ eb,
    unsigned long long* __restrict__ partial64, int n_edges, int np_pad, int range)
{
    extern __shared__ unsigned long long lds64[];
    const int r = blockIdx.x / NB5FB;
    const int c = blockIdx.x % NB5FB;
    const int node0 = r * range;
    for (int w = threadIdx.x; w < range; w += SCANT) lds64[w] = 0ULL;
    __syncthreads();
    const F3* __restrict__ P = (const F3*)points;
    const int chunk = (n_edges + NB5FB - 1) / NB5FB;
    const int e0 = c * chunk, e1 = min(n_edges, e0 + chunk);
    for (int e = e0 + (int)threadIdx.x; e < e1; e += SCANT) {
        int a = ea[e], b = eb[e];
        int la = a - node0, lb = b - node0;
        bool ha = (unsigned)la < (unsigned)range;
        bool hb = (unsigned)lb < (unsigned)range;
        if (ha || hb) {
            F3 pa = P[a], pb = P[b];
            float vx = pb.x - pa.x, vy = pb.y - pa.y, vz = pb.z - pa.z;
            float s = -force[e] * rsqrtf(vx * vx + vy * vy + vz * vz);
            int qx = __float2int_rn(s * vx * QSCALE);
            int qy = __float2int_rn(s * vy * QSCALE);
            int qz = __float2int_rn(s * vz * QSCALE);
            qx = max(-32767, min(32767, qx));
            qy = max(-32767, min(32767, qy));
            qz = max(-32767, min(32767, qz));
            long long v = (long long)qx + ((long long)qy << 21) + ((long long)qz << 42);
            if (ha) atomicAdd(&lds64[la], (unsigned long long)v);
            if (hb) atomicAdd(&lds64[lb], (unsigned long long)(-v));
        }
    }
    __syncthreads();
    unsigned long long* dst = partial64 + (size_t)c * (size_t)np_pad + node0;
    for (int w = threadIdx.x; w < range; w += SCANT) dst[w] = lds64[w];
}

__global__ void reduce64fb_kernel(const float* __restrict__ ext,
                                  const unsigned long long* __restrict__ partial64,
                                  float* __restrict__ out, int n_points, int np_pad)
{
    int i = blockIdx.x * blockDim.x + threadIdx.x;
    if (i >= n_points) return;
    unsigned long long t = 0ULL;
#pragma unroll 4
    for (int c = 0; c < NB5FB; ++c)
        t += partial64[(size_t)c * (size_t)np_pad + i];
    long long T = (long long)t;
    long long X = ((long long)((unsigned long long)T << 43)) >> 43;
    T = (T - X) >> 21;
    long long Y = ((long long)((unsigned long long)T << 43)) >> 43;
    T = (T - Y) >> 21;
    long long Z = ((long long)((unsigned long long)T << 42)) >> 42;
    const float inv = 1.0f / QSCALE;
    out[3 * i + 0] = ext[3 * i + 0] + (float)X * inv;
    out[3 * i + 1] = ext[3 * i + 1] + (float)Y * inv;
    out[3 * i + 2] = ext[3 * i + 2] + (float)Z * inv;
}

extern "C" void kernel_launch(void* const* d_in, const int* in_sizes, int n_in,
                              void* d_out, int out_size, void* d_ws, size_t ws_size,
                              hipStream_t stream) {
    const float* points = (const float*)d_in[0];
    const float* ext_f  = (const float*)d_in[1];
    const float* force  = (const float*)d_in[2];
    const int*   ea     = (const int*)d_in[3];
    const int*   eb     = (const int*)d_in[4];
    float* out = (float*)d_out;
    char*  ws  = (char*)d_ws;

    const int n_edges  = in_sizes[2];
    const int total    = out_size;                       // n_points*3
    const int n_points = total / 3;

    const int range5  = (n_points + NR5 - 1) / NR5;      // 20000
    const int np_pad  = range5 * NR5;
    const unsigned magic = (unsigned)((0x100000000ULL + range5 - 1) / (unsigned)range5);
    const int chunk = (((n_edges + NWAVE - 1) / NWAVE) + 3) & ~3;   // x4 aligned

    // static range segment capacity: mean + ~7-sigma slack, 64-aligned
    const unsigned epr = (unsigned)(((unsigned long long)2 * n_edges) / NR5);
    const unsigned cap = (epr + epr / 256 + 63u) & ~63u;            // ~2.570M

    const size_t lds_consume = (size_t)range5 * sizeof(unsigned long long); // 160000
    const size_t entries_b = (size_t)NR5 * cap * sizeof(uint2);             // ~102.8MB
    const size_t partial_b = (size_t)NSLICE * (size_t)np_pad * sizeof(unsigned long long); // 35.2MB
    const size_t row_b     = (size_t)NROW * NWAVE * sizeof(unsigned);       // 655KB
    const size_t tail_b    = 4096;
    const size_t need_new  = entries_b + ((2 * row_b > partial_b) ? 2 * row_b : partial_b) + tail_b;

    const size_t partfb_b  = (size_t)NB5FB * (size_t)np_pad * sizeof(unsigned long long);

    hipFuncSetAttribute((const void*)consume_kernel,
                        hipFuncAttributeMaxDynamicSharedMemorySize, (int)lds_consume);
    hipFuncSetAttribute((const void*)scan64_kernel,
                        hipFuncAttributeMaxDynamicSharedMemorySize, (int)lds_consume);

    const int rb = 256;

    if (range5 <= 0xFFFF && lds_consume <= 160 * 1024 && ws_size >= need_new) {
        uint2* entries = (uint2*)ws;
        unsigned long long* partial64 = (unsigned long long*)(ws + entries_b);
        unsigned* counts     = (unsigned*)(ws + entries_b);            // aliases partial
        unsigned* waveprefix = counts + (size_t)NROW * NWAVE;          // aliases partial
        unsigned* rowoffset   = (unsigned*)(ws + ws_size - tail_b);    // survives consume
        unsigned* rangetotals = rowoffset + NROW;

        count_kernel<<<NWAVE / (K1T / 64), K1T, 0, stream>>>(
            ea, eb, counts, n_edges, chunk, magic);
        scan_kernel<<<NR5, 512, 0, stream>>>(counts, waveprefix, rowoffset, rangetotals);
        emit_kernel<<<NBLD3, K3T, 0, stream>>>(
            points, force, ea, eb, waveprefix, rowoffset, entries,
            n_edges, chunk, range5, magic, cap);
        consume_kernel<<<NR5 * NSLICE, K4T, lds_consume, stream>>>(
            (const ushort4*)entries, rangetotals, partial64, np_pad, range5, cap);
        reduce64_kernel<<<(n_points + rb - 1) / rb, rb, 0, stream>>>(
            ext_f, partial64, out, n_points, np_pad);
    } else if (lds_consume <= 160 * 1024 && ws_size >= partfb_b) {
        unsigned long long* partial64 = (unsigned long long*)ws;
        scan64_kernel<<<NR5 * NB5FB, SCANT, lds_consume, stream>>>(
            points, force, ea, eb, partial64, n_edges, np_pad, range5);
        reduce64fb_kernel<<<(n_points + rb - 1) / rb, rb, 0, stream>>>(
            ext_f, partial64, out, n_points, np_pad);
    } else {
        hipMemcpyAsync(d_out, (const void*)ext_f, (size_t)total * sizeof(float),
                       hipMemcpyDeviceToDevice, stream);
        struct L {
            static __global__ void k(const float* P, const float* F,
                                     const int* A, const int* B, float* O, int n) {
                int e = blockIdx.x * blockDim.x + threadIdx.x;
                if (e >= n) return;
                int a = A[e], b = B[e];
                float ax = P[3*a], ay = P[3*a+1], az = P[3*a+2];
                float bx = P[3*b], by = P[3*b+1], bz = P[3*b+2];
                float vx = bx-ax, vy = by-ay, vz = bz-az;
                float s = -F[e] * rsqrtf(vx*vx+vy*vy+vz*vz);
                atomicAdd(&O[3*a+0], s*vx); atomicAdd(&O[3*a+1], s*vy); atomicAdd(&O[3*a+2], s*vz);
                atomicAdd(&O[3*b+0], -s*vx); atomicAdd(&O[3*b+1], -s*vy); atomicAdd(&O[3*b+2], -s*vz);
            }
        };
        L::k<<<(n_edges + 255) / 256, 256, 0, stream>>>(points, force, ea, eb, out, n_edges);
    }
}

// Round 14
// 134.171 us; speedup vs baseline: 1.3191x; 1.1365x over previous
//
#include <hip/hip_runtime.h>

// graph_56006373539875: per-edge spring-force scatter.
// R1 1881us -> R2 240 -> R5 165 -> R7 144 -> R10 135.7us (BEST).
// R11: occupancy 32->50% => emit unchanged (98us) -> per-CU shared pipe.
// R12: count-fusion regressed (154us, extra fetch + serial dependency).
// R13: 8x counter fan-out regressed (133us emit, store locality loss,
//      WRITE 108->154MB) => LDS same-address serialization NOT the wall.
// Conclusion: emit's 98us = TA/VMEM address-processing floor on ~25.6M
//      scattered lane-ops (12.8M 12B gathers + 12.8M 8B scatter stores,
//      ~2.3cyc/lane-op/CU), invariant to occupancy & LDS contention.
//      All other phases at pipe floors (count~10 stream BW, scan~4,
//      consume~14 @0.56cyc ds_add_u64, reduce~7).
// R14: revert to R10-exact (best measured).

#define NR5    5
#define NWAVE  4096
#define K1T    1024              // count: 16 waves/block -> 256 blocks
#define EWAVES 8                 // emit: 8 waves/block -> 512 blocks
#define K3T    (EWAVES * 64)
#define NBLD3  (NWAVE / EWAVES)
#define K4T    1024
#define NSLICE 44                // consume slices/range -> grid 220
#define QSCALE 4096.0f

struct __attribute__((packed, aligned(4))) F3 { float x, y, z; };

// ---------------- K1: per-WAVE per-range endpoint counts ------------------
__global__ __launch_bounds__(K1T) void count_kernel(
    const int* __restrict__ ea, const int* __restrict__ eb,
    unsigned* __restrict__ counts,           // [NR5][NWAVE]
    int n_edges, int chunk, unsigned magic)
{
    const int wid  = blockIdx.x * (K1T / 64) + ((int)threadIdx.x >> 6);
    const int lane = (int)threadIdx.x & 63;
    const int e0 = min(n_edges, wid * chunk);
    const int e1 = min(n_edges, e0 + chunk);
    const int nvec = (e1 - e0) & ~3;

    unsigned c[NR5];
#pragma unroll
    for (int j = 0; j < NR5; ++j) c[j] = 0;

    const int4* ea4 = (const int4*)(ea + e0);
    const int4* eb4 = (const int4*)(eb + e0);
    for (int g = lane; g < (nvec >> 2); g += 64) {
        int4 a4 = ea4[g];
        int4 b4 = eb4[g];
        unsigned r0 = __umulhi((unsigned)a4.x, magic), s0 = __umulhi((unsigned)b4.x, magic);
        unsigned r1 = __umulhi((unsigned)a4.y, magic), s1 = __umulhi((unsigned)b4.y, magic);
        unsigned r2 = __umulhi((unsigned)a4.z, magic), s2 = __umulhi((unsigned)b4.z, magic);
        unsigned r3 = __umulhi((unsigned)a4.w, magic), s3 = __umulhi((unsigned)b4.w, magic);
#pragma unroll
        for (int j = 0; j < NR5; ++j)
            c[j] += (r0 == (unsigned)j) + (s0 == (unsigned)j)
                  + (r1 == (unsigned)j) + (s1 == (unsigned)j)
                  + (r2 == (unsigned)j) + (s2 == (unsigned)j)
                  + (r3 == (unsigned)j) + (s3 == (unsigned)j);
    }
    for (int e = e0 + nvec + lane; e < e1; e += 64) {
        unsigned ra = __umulhi((unsigned)ea[e], magic);
        unsigned rb = __umulhi((unsigned)eb[e], magic);
#pragma unroll
        for (int j = 0; j < NR5; ++j)
            c[j] += (ra == (unsigned)j) + (rb == (unsigned)j);
    }
#pragma unroll
    for (int j = 0; j < NR5; ++j) {
        unsigned v = c[j];
#pragma unroll
        for (int off = 32; off > 0; off >>= 1) v += __shfl_down(v, off);
        if (lane == 0) counts[j * NWAVE + wid] = v;
    }
}

// ---------------- K2: exclusive prefix over waves, per range --------------
__global__ __launch_bounds__(NR5 * 64) void scan_kernel(
    const unsigned* __restrict__ counts,
    unsigned* __restrict__ waveprefix,
    unsigned* __restrict__ rangetotals)
{
    const int j    = (int)threadIdx.x >> 6;
    const int lane = (int)threadIdx.x & 63;
    unsigned running = 0;
    for (int c = 0; c < NWAVE / 64; ++c) {
        const int idx = c * 64 + lane;
        unsigned v = counts[j * NWAVE + idx];
        const unsigned orig = v;
#pragma unroll
        for (int off = 1; off < 64; off <<= 1) {
            unsigned t = __shfl_up(v, off);
            if (lane >= off) v += t;
        }
        waveprefix[j * NWAVE + idx] = running + v - orig;
        running += __shfl(v, 63);
    }
    if (lane == 0) rangetotals[j] = running;
}

// ---------------- K3: emit via LDS-counter slot alloc + direct store ------
__global__ __launch_bounds__(K3T) void emit_kernel(
    const float* __restrict__ points, const float* __restrict__ force,
    const int* __restrict__ ea, const int* __restrict__ eb,
    const unsigned* __restrict__ waveprefix, const unsigned* __restrict__ rangetotals,
    uint2* __restrict__ entries,             // [2*n_edges] {id|qx<<16, qy|qz<<16}
    int n_edges, int chunk, int range, unsigned magic)
{
    __shared__ unsigned cnt[EWAVES][NR5];
    const int wslot = (int)threadIdx.x >> 6;
    const int lane  = (int)threadIdx.x & 63;
    const int wid   = blockIdx.x * EWAVES + wslot;

    if (lane < NR5) {
        unsigned base = 0;
        for (int k = 0; k < lane; ++k) base += rangetotals[k];
        cnt[wslot][lane] = base + waveprefix[lane * NWAVE + wid];
    }
    __syncthreads();

    const F3* __restrict__ P = (const F3*)points;
    const int e0 = min(n_edges, wid * chunk);
    const int e1 = min(n_edges, e0 + chunk);
    const int nvec = (e1 - e0) & ~3;

    const int4*   ea4 = (const int4*)(ea + e0);
    const int4*   eb4 = (const int4*)(eb + e0);
    const float4* ff4 = (const float4*)(force + e0);

#define PROCE(pa, pb, fsc, aa, bb)                                               \
    {                                                                            \
        float vx = pb.x - pa.x, vy = pb.y - pa.y, vz = pb.z - pa.z;              \
        float s  = -(fsc) * rsqrtf(vx * vx + vy * vy + vz * vz);                 \
        int qx = __float2int_rn(s * vx * QSCALE);                                \
        int qy = __float2int_rn(s * vy * QSCALE);                                \
        int qz = __float2int_rn(s * vz * QSCALE);                                \
        qx = max(-32767, min(32767, qx));                                        \
        qy = max(-32767, min(32767, qy));                                        \
        qz = max(-32767, min(32767, qz));                                        \
        unsigned ra = __umulhi((unsigned)(aa), magic);                           \
        unsigned rb = __umulhi((unsigned)(bb), magic);                           \
        unsigned ida = (unsigned)(aa) - ra * (unsigned)range;                    \
        unsigned idb = (unsigned)(bb) - rb * (unsigned)range;                    \
        uint2 entA, entB;                                                        \
        entA.x = ida | ((unsigned)(unsigned short)(short)qx << 16);              \
        entA.y = (unsigned)(unsigned short)(short)qy                             \
               | ((unsigned)(unsigned short)(short)qz << 16);                    \
        entB.x = idb | ((unsigned)(unsigned short)(short)(-qx) << 16);           \
        entB.y = (unsigned)(unsigned short)(short)(-qy)                          \
               | ((unsigned)(unsigned short)(short)(-qz) << 16);                 \
        unsigned sA = atomicAdd(&cnt[wslot][ra], 1u);                            \
        entries[sA] = entA;                                                      \
        unsigned sB = atomicAdd(&cnt[wslot][rb], 1u);                            \
        entries[sB] = entB;                                                      \
    }

    for (int g = lane; g < (nvec >> 2); g += 64) {
        int4   a4 = ea4[g];
        int4   b4 = eb4[g];
        float4 f4 = ff4[g];
        // issue all 8 gathers before any math (MLP)
        F3 pa0 = P[a4.x]; F3 pb0 = P[b4.x];
        F3 pa1 = P[a4.y]; F3 pb1 = P[b4.y];
        F3 pa2 = P[a4.z]; F3 pb2 = P[b4.z];
        F3 pa3 = P[a4.w]; F3 pb3 = P[b4.w];
        PROCE(pa0, pb0, f4.x, a4.x, b4.x)
        PROCE(pa1, pb1, f4.y, a4.y, b4.y)
        PROCE(pa2, pb2, f4.z, a4.z, b4.z)
        PROCE(pa3, pb3, f4.w, a4.w, b4.w)
    }
    for (int e = e0 + nvec + lane; e < e1; e += 64) {
        int a = ea[e], b = eb[e];
        F3 pa = P[a], pb = P[b];
        float f = force[e];
        PROCE(pa, pb, f, a, b)
    }
#undef PROCE
}

// ---------------- K4: dense consume, ONE ds_add_u64 per entry -------------
__global__ __launch_bounds__(K4T) void consume_kernel(
    const ushort4* __restrict__ entries, const unsigned* __restrict__ rangetotals,
    unsigned long long* __restrict__ partial64,   // [NSLICE][np_pad]
    int np_pad, int range)
{
    extern __shared__ unsigned long long lds64[];   // [range]
    const int r     = blockIdx.x % NR5;
    const int slice = blockIdx.x / NR5;

    unsigned base = 0;
    for (int j = 0; j < r; ++j) base += rangetotals[j];
    const unsigned cnt = rangetotals[r];
    const unsigned lo = base + (unsigned)((unsigned long long)cnt * slice / NSLICE);
    const unsigned hi = base + (unsigned)((unsigned long long)cnt * (slice + 1) / NSLICE);

    for (int w = threadIdx.x; w < range; w += K4T) lds64[w] = 0ULL;
    __syncthreads();

    for (unsigned i = lo + threadIdx.x; i < hi; i += K4T) {
        ushort4 q = entries[i];
        long long v = (long long)(short)q.y
                    + ((long long)(short)q.z << 21)
                    + ((long long)(short)q.w << 42);
        atomicAdd(&lds64[q.x], (unsigned long long)v);
    }
    __syncthreads();

    unsigned long long* dst = partial64 + (size_t)slice * (size_t)np_pad
                            + (size_t)r * (size_t)range;
    for (int w = threadIdx.x; w < range; w += K4T) dst[w] = lds64[w];
}

// ---------------- K5: exact u64 reduce -> decode -> + ext -----------------
__global__ void reduce64_kernel(const float* __restrict__ ext,
                                const unsigned long long* __restrict__ partial64,
                                float* __restrict__ out, int n_points, int np_pad)
{
    int i = blockIdx.x * blockDim.x + threadIdx.x;
    if (i >= n_points) return;
    unsigned long long t = 0ULL;
#pragma unroll 4
    for (int c = 0; c < NSLICE; ++c)
        t += partial64[(size_t)c * (size_t)np_pad + i];

    long long T = (long long)t;
    long long X = ((long long)((unsigned long long)T << 43)) >> 43;
    T = (T - X) >> 21;
    long long Y = ((long long)((unsigned long long)T << 43)) >> 43;
    T = (T - Y) >> 21;
    long long Z = ((long long)((unsigned long long)T << 42)) >> 42;

    const float inv = 1.0f / QSCALE;
    out[3 * i + 0] = ext[3 * i + 0] + (float)X * inv;
    out[3 * i + 1] = ext[3 * i + 1] + (float)Y * inv;
    out[3 * i + 2] = ext[3 * i + 2] + (float)Z * inv;
}

// ---------------- fallback: fused u64 scan (R8, known 138us) --------------
#define NB5FB 48
#define SCANT 1024
__global__ __launch_bounds__(SCANT) void scan64_kernel(
    const float* __restrict__ points, const float* __restrict__ force,
    const int* __restrict__ ea, const int* __restrict__ eb,
    unsigned long long* __restrict__ partial64, int n_edges, int np_pad, int range)
{
    extern __shared__ unsigned long long lds64[];
    const int r = blockIdx.x / NB5FB;
    const int c = blockIdx.x % NB5FB;
    const int node0 = r * range;
    for (int w = threadIdx.x; w < range; w += SCANT) lds64[w] = 0ULL;
    __syncthreads();
    const F3* __restrict__ P = (const F3*)points;
    const int chunk = (n_edges + NB5FB - 1) / NB5FB;
    const int e0 = c * chunk, e1 = min(n_edges, e0 + chunk);
    for (int e = e0 + (int)threadIdx.x; e < e1; e += SCANT) {
        int a = ea[e], b = eb[e];
        int la = a - node0, lb = b - node0;
        bool ha = (unsigned)la < (unsigned)range;
        bool hb = (unsigned)lb < (unsigned)range;
        if (ha || hb) {
            F3 pa = P[a], pb = P[b];
            float vx = pb.x - pa.x, vy = pb.y - pa.y, vz = pb.z - pa.z;
            float s = -force[e] * rsqrtf(vx * vx + vy * vy + vz * vz);
            int qx = __float2int_rn(s * vx * QSCALE);
            int qy = __float2int_rn(s * vy * QSCALE);
            int qz = __float2int_rn(s * vz * QSCALE);
            qx = max(-32767, min(32767, qx));
            qy = max(-32767, min(32767, qy));
            qz = max(-32767, min(32767, qz));
            long long v = (long long)qx + ((long long)qy << 21) + ((long long)qz << 42);
            if (ha) atomicAdd(&lds64[la], (unsigned long long)v);
            if (hb) atomicAdd(&lds64[lb], (unsigned long long)(-v));
        }
    }
    __syncthreads();
    unsigned long long* dst = partial64 + (size_t)c * (size_t)np_pad + node0;
    for (int w = threadIdx.x; w < range; w += SCANT) dst[w] = lds64[w];
}

__global__ void reduce64fb_kernel(const float* __restrict__ ext,
                                  const unsigned long long* __restrict__ partial64,
                                  float* __restrict__ out, int n_points, int np_pad)
{
    int i = blockIdx.x * blockDim.x + threadIdx.x;
    if (i >= n_points) return;
    unsigned long long t = 0ULL;
#pragma unroll 4
    for (int c = 0; c < NB5FB; ++c)
        t += partial64[(size_t)c * (size_t)np_pad + i];
    long long T = (long long)t;
    long long X = ((long long)((unsigned long long)T << 43)) >> 43;
    T = (T - X) >> 21;
    long long Y = ((long long)((unsigned long long)T << 43)) >> 43;
    T = (T - Y) >> 21;
    long long Z = ((long long)((unsigned long long)T << 42)) >> 42;
    const float inv = 1.0f / QSCALE;
    out[3 * i + 0] = ext[3 * i + 0] + (float)X * inv;
    out[3 * i + 1] = ext[3 * i + 1] + (float)Y * inv;
    out[3 * i + 2] = ext[3 * i + 2] + (float)Z * inv;
}

extern "C" void kernel_launch(void* const* d_in, const int* in_sizes, int n_in,
                              void* d_out, int out_size, void* d_ws, size_t ws_size,
                              hipStream_t stream) {
    const float* points = (const float*)d_in[0];
    const float* ext_f  = (const float*)d_in[1];
    const float* force  = (const float*)d_in[2];
    const int*   ea     = (const int*)d_in[3];
    const int*   eb     = (const int*)d_in[4];
    float* out = (float*)d_out;
    char*  ws  = (char*)d_ws;

    const int n_edges  = in_sizes[2];
    const int total    = out_size;                       // n_points*3
    const int n_points = total / 3;

    const int range5  = (n_points + NR5 - 1) / NR5;      // 20000
    const int np_pad  = range5 * NR5;
    const unsigned magic = (unsigned)((0x100000000ULL + range5 - 1) / (unsigned)range5);
    const int chunk = (((n_edges + NWAVE - 1) / NWAVE) + 3) & ~3;   // x4 aligned

    const size_t lds_consume = (size_t)range5 * sizeof(unsigned long long); // 160000
    const size_t entries_b = (size_t)2 * n_edges * sizeof(uint2);           // 102.4MB
    const size_t partial_b = (size_t)NSLICE * (size_t)np_pad * sizeof(unsigned long long); // 35.2MB
    const size_t cnt_b     = (size_t)NR5 * NWAVE * sizeof(unsigned);        // 80KB
    const size_t tail_need = (2 * cnt_b > partial_b) ? 2 * cnt_b : partial_b;
    const size_t need_new  = entries_b + tail_need + 64;

    const size_t partfb_b  = (size_t)NB5FB * (size_t)np_pad * sizeof(unsigned long long);

    hipFuncSetAttribute((const void*)consume_kernel,
                        hipFuncAttributeMaxDynamicSharedMemorySize, (int)lds_consume);
    hipFuncSetAttribute((const void*)scan64_kernel,
                        hipFuncAttributeMaxDynamicSharedMemorySize, (int)lds_consume);

    const int rb = 256;

    if (range5 <= 0xFFFF && lds_consume <= 160 * 1024 && ws_size >= need_new) {
        uint2*    entries     = (uint2*)ws;
        unsigned long long* partial64 = (unsigned long long*)(ws + entries_b);
        unsigned* counts      = (unsigned*)(ws + entries_b);           // aliases partial64
        unsigned* waveprefix  = counts + (size_t)NR5 * NWAVE;
        unsigned* rangetotals = (unsigned*)(ws + ws_size - 64);        // survives K4

        count_kernel<<<NWAVE / (K1T / 64), K1T, 0, stream>>>(
            ea, eb, counts, n_edges, chunk, magic);
        scan_kernel<<<1, NR5 * 64, 0, stream>>>(counts, waveprefix, rangetotals);
        emit_kernel<<<NBLD3, K3T, 0, stream>>>(
            points, force, ea, eb, waveprefix, rangetotals, entries,
            n_edges, chunk, range5, magic);
        consume_kernel<<<NR5 * NSLICE, K4T, lds_consume, stream>>>(
            (const ushort4*)entries, rangetotals, partial64, np_pad, range5);
        reduce64_kernel<<<(n_points + rb - 1) / rb, rb, 0, stream>>>(
            ext_f, partial64, out, n_points, np_pad);
    } else if (lds_consume <= 160 * 1024 && ws_size >= partfb_b) {
        unsigned long long* partial64 = (unsigned long long*)ws;
        scan64_kernel<<<NR5 * NB5FB, SCANT, lds_consume, stream>>>(
            points, force, ea, eb, partial64, n_edges, np_pad, range5);
        reduce64fb_kernel<<<(n_points + rb - 1) / rb, rb, 0, stream>>>(
            ext_f, partial64, out, n_points, np_pad);
    } else {
        hipMemcpyAsync(d_out, (const void*)ext_f, (size_t)total * sizeof(float),
                       hipMemcpyDeviceToDevice, stream);
        struct L {
            static __global__ void k(const float* P, const float* F,
                                     const int* A, const int* B, float* O, int n) {
                int e = blockIdx.x * blockDim.x + threadIdx.x;
                if (e >= n) return;
                int a = A[e], b = B[e];
                float ax = P[3*a], ay = P[3*a+1], az = P[3*a+2];
                float bx = P[3*b], by = P[3*b+1], bz = P[3*b+2];
                float vx = bx-ax, vy = by-ay, vz = bz-az;
                float s = -F[e] * rsqrtf(vx*vx+vy*vy+vz*vz);
                atomicAdd(&O[3*a+0], s*vx); atomicAdd(&O[3*a+1], s*vy); atomicAdd(&O[3*a+2], s*vz);
                atomicAdd(&O[3*b+0], -s*vx); atomicAdd(&O[3*b+1], -s*vy); atomicAdd(&O[3*b+2], -s*vz);
            }
        };
        L::k<<<(n_edges + 255) / 256, 256, 0, stream>>>(points, force, ea, eb, out, n_edges);
    }
}